// Round 1
// 246.226 us; speedup vs baseline: 1.0384x; 1.0384x over previous
//
#include <hip/hip_runtime.h>
#include <math.h>
#include <stdint.h>

// Problem: B=8, N=1024, ME=1024, D=1024, fp32 in/out.
// a = sigmoid(z @ M @ e^T); A = softmax(a, axis=N); e_out = A @ e.
// Outputs concatenated: e_out [B,N,D] then A [B,N,ME].
//
// Round 8: gemm3 de-VALU-ified.
//  - NEW escale_kernel (post-gemm2): eTs[b][d][m] = (bf16)(e[b][m][d]/colsum[b][m]),
//    written into the zM_hi buffer (dead after gemm2) -> no extra workspace.
//  - gemm3 is now a pure DMA-staged bf16 NT-GEMM (stage_bf16 both operands,
//    32 MFMA/K-step, 32 KB LDS). The per-K-step register transpose + rsm
//    scaling (the old VALU bottleneck, redone 8x per batch) is gone.
//  - A = P/s slice split over 2 grid z-slices (128 blocks) to reduce straggle.
//  - gemm1/gemm2/prep unchanged (structurally pinned at ~33% MfmaUtil;
//    8-phase rewrite is a future round).

typedef __bf16 bf16_8 __attribute__((ext_vector_type(8)));
typedef __bf16 bf16_4 __attribute__((ext_vector_type(4)));
typedef float  f32_4  __attribute__((ext_vector_type(4)));

// ---------------------------------------------------------------------------
__device__ __forceinline__ void gload_lds16(const __bf16* g, __bf16* l) {
    __builtin_amdgcn_global_load_lds(
        (const __attribute__((address_space(1))) void*)g,
        (__attribute__((address_space(3))) void*)l, 16, 0, 0);
}

__device__ __forceinline__ int swz8(int r) { return (r ^ (r >> 2)) & 7; }

// Stage a 128x64 bf16 tile via global_load_lds. Row r, LDS slot s holds global
// 16B-chunk s ^ swz8(r). 1024 chunks = 4 x 256 threads.
__device__ __forceinline__ void stage_bf16(const __bf16* __restrict__ g, int ldK,
                                           int k0, __bf16* lds, int tid) {
#pragma unroll
    for (int t = 0; t < 4; ++t) {
        const int c = t * 256 + tid;
        const int row = c >> 3, slot = c & 7;
        gload_lds16(g + (long long)row * ldK + k0 + (slot ^ swz8(row)) * 8,
                    lds + (t * 256 + (tid >> 6) * 64) * 8);
    }
}

// Stage a 128x64 tile from an fp32 source, split to hi/lo bf16 (no transpose).
// 128 rows x 16 float4/row = 2048 float4 = 8 passes x 256 threads.
__device__ __forceinline__ void stage_f32_split(const float* __restrict__ g, int ldK,
                                                int k0, __bf16* sH, __bf16* sL, int tid) {
#pragma unroll
    for (int p = 0; p < 8; ++p) {
        const int qi = p * 256 + tid;
        const int row = qi >> 4, kq4 = qi & 15;
        const float4 v = *(const float4*)(g + (long long)row * ldK + k0 + kq4 * 4);
        const int off = row * 64 + (((kq4 >> 1) ^ swz8(row)) * 8) + (kq4 & 1) * 4;
        bf16_4 h, l;
        h[0] = (__bf16)v.x; l[0] = (__bf16)(v.x - (float)h[0]);
        h[1] = (__bf16)v.y; l[1] = (__bf16)(v.y - (float)h[1]);
        h[2] = (__bf16)v.z; l[2] = (__bf16)(v.z - (float)h[2]);
        h[3] = (__bf16)v.w; l[3] = (__bf16)(v.w - (float)h[3]);
        *(bf16_4*)(sH + off) = h;
        *(bf16_4*)(sL + off) = l;
    }
}

// Fragment LDS offset (bf16 units): row r, k-chunk cK (0..7).
__device__ __forceinline__ int frag_off(int r, int cK) {
    return r * 64 + ((cK ^ swz8(r)) * 8);
}

// ---------------------------------------------------------------------------
// GEMM1: zM = z @ M (via M^T, NT). A = z fp32 self-staged split; B = MT hi/lo.
// Out: zM hi/lo bf16. Grid (8 colblk, 64 rowblk).
__global__ __launch_bounds__(256) void gemm1_kernel(
    const float* __restrict__ z,
    const __bf16* __restrict__ MT_hi, const __bf16* __restrict__ MT_lo,
    __bf16* __restrict__ zM_hi, __bf16* __restrict__ zM_lo)
{
    const int D = 1024;
    __shared__ __bf16 sAh[8192], sAl[8192], sBh[8192], sBl[8192];
    const int tid = threadIdx.x, lane = tid & 63, w = tid >> 6;
    const int fr = lane & 15, q = lane >> 4;
    const int wr = (w >> 1) * 64, wc = (w & 1) * 64;

    const float*  pA  = z     + (long long)blockIdx.y * 128 * D;
    const __bf16* pBh = MT_hi + (long long)blockIdx.x * 128 * D;
    const __bf16* pBl = MT_lo + (long long)blockIdx.x * 128 * D;

    f32_4 acc[4][4];
#pragma unroll
    for (int i = 0; i < 4; ++i)
#pragma unroll
        for (int j = 0; j < 4; ++j) acc[i][j] = (f32_4){0.f, 0.f, 0.f, 0.f};

    for (int k0 = 0; k0 < D; k0 += 64) {
        stage_bf16(pBh, D, k0, sBh, tid);           // DMA first...
        stage_bf16(pBl, D, k0, sBl, tid);
        stage_f32_split(pA, D, k0, sAh, sAl, tid);  // ...VALU staging overlaps
        __syncthreads();
#pragma unroll
        for (int ch = 0; ch < 2; ++ch) {
            bf16_8 ah[4], al[4], bh[4], bl[4];
#pragma unroll
            for (int i = 0; i < 4; ++i) {
                const int oA = frag_off(wr + 16 * i + fr, ch * 4 + q);
                ah[i] = *(const bf16_8*)(sAh + oA);
                al[i] = *(const bf16_8*)(sAl + oA);
                const int oB = frag_off(wc + 16 * i + fr, ch * 4 + q);
                bh[i] = *(const bf16_8*)(sBh + oB);
                bl[i] = *(const bf16_8*)(sBl + oB);
            }
#pragma unroll
            for (int i = 0; i < 4; ++i)
#pragma unroll
                for (int j = 0; j < 4; ++j) {
                    acc[i][j] = __builtin_amdgcn_mfma_f32_16x16x32_bf16(ah[i], bh[j], acc[i][j], 0, 0, 0);
                    acc[i][j] = __builtin_amdgcn_mfma_f32_16x16x32_bf16(ah[i], bl[j], acc[i][j], 0, 0, 0);
                    acc[i][j] = __builtin_amdgcn_mfma_f32_16x16x32_bf16(al[i], bh[j], acc[i][j], 0, 0, 0);
                }
        }
        __syncthreads();
    }

    const int row0 = blockIdx.y * 128 + wr;
    const int col0 = blockIdx.x * 128 + wc;
#pragma unroll
    for (int i = 0; i < 4; ++i)
#pragma unroll
        for (int j = 0; j < 4; ++j) {
            const int col = col0 + 16 * j + fr;
#pragma unroll
            for (int reg = 0; reg < 4; ++reg) {
                const int row = row0 + 16 * i + q * 4 + reg;
                const float v = acc[i][j][reg];
                const long long idx = (long long)row * D + col;
                const __bf16 h = (__bf16)v;
                zM_hi[idx] = h;
                zM_lo[idx] = (__bf16)(v - (float)h);
            }
        }
}

// ---------------------------------------------------------------------------
// GEMM2: P = exp(sigmoid(zM @ e^T)) per batch (NT), bf16 out + colsum atomics.
// A = zM hi/lo via DMA; B = e fp32 self-staged split.
// Grid (8,8,8), batch = blockIdx.x (XCD locality).
__global__ __launch_bounds__(256) void gemm2_kernel(
    const __bf16* __restrict__ zM_hi, const __bf16* __restrict__ zM_lo,
    const float* __restrict__ e,
    __bf16* __restrict__ P_bf, float* __restrict__ sums)
{
    const int D = 1024, N = 1024, ME = 1024;
    __shared__ __bf16 sAh[8192], sAl[8192], sBh[8192], sBl[8192];
    const int tid = threadIdx.x, lane = tid & 63, w = tid >> 6;
    const int fr = lane & 15, q = lane >> 4;
    const int wr = (w >> 1) * 64, wc = (w & 1) * 64;
    const int bz = blockIdx.x, rowb = blockIdx.y, colb = blockIdx.z;

    const __bf16* pAh = zM_hi + ((long long)bz * N + rowb * 128) * D;
    const __bf16* pAl = zM_lo + ((long long)bz * N + rowb * 128) * D;
    const float*  pB  = e     + ((long long)bz * ME + colb * 128) * D;

    f32_4 acc[4][4];
#pragma unroll
    for (int i = 0; i < 4; ++i)
#pragma unroll
        for (int j = 0; j < 4; ++j) acc[i][j] = (f32_4){0.f, 0.f, 0.f, 0.f};

    for (int k0 = 0; k0 < D; k0 += 64) {
        stage_bf16(pAh, D, k0, sAh, tid);
        stage_bf16(pAl, D, k0, sAl, tid);
        stage_f32_split(pB, D, k0, sBh, sBl, tid);
        __syncthreads();
#pragma unroll
        for (int ch = 0; ch < 2; ++ch) {
            bf16_8 ah[4], al[4], bh[4], bl[4];
#pragma unroll
            for (int i = 0; i < 4; ++i) {
                const int oA = frag_off(wr + 16 * i + fr, ch * 4 + q);
                ah[i] = *(const bf16_8*)(sAh + oA);
                al[i] = *(const bf16_8*)(sAl + oA);
                const int oB = frag_off(wc + 16 * i + fr, ch * 4 + q);
                bh[i] = *(const bf16_8*)(sBh + oB);
                bl[i] = *(const bf16_8*)(sBl + oB);
            }
#pragma unroll
            for (int i = 0; i < 4; ++i)
#pragma unroll
                for (int j = 0; j < 4; ++j) {
                    acc[i][j] = __builtin_amdgcn_mfma_f32_16x16x32_bf16(ah[i], bh[j], acc[i][j], 0, 0, 0);
                    acc[i][j] = __builtin_amdgcn_mfma_f32_16x16x32_bf16(ah[i], bl[j], acc[i][j], 0, 0, 0);
                    acc[i][j] = __builtin_amdgcn_mfma_f32_16x16x32_bf16(al[i], bh[j], acc[i][j], 0, 0, 0);
                }
        }
        __syncthreads();
    }

    const int row0 = rowb * 128 + wr;
    const int col0 = colb * 128 + wc;
    float cs[4] = {0.f, 0.f, 0.f, 0.f};
#pragma unroll
    for (int i = 0; i < 4; ++i)
#pragma unroll
        for (int j = 0; j < 4; ++j) {
            const int col = col0 + 16 * j + fr;
#pragma unroll
            for (int reg = 0; reg < 4; ++reg) {
                const int row = row0 + 16 * i + q * 4 + reg;
                float v = acc[i][j][reg];
                const float s = 1.0f / (1.0f + __expf(-v));
                v = __expf(s);
                P_bf[(long long)bz * N * ME + (long long)row * ME + col] = (__bf16)v;
                cs[j] += v;
            }
        }
#pragma unroll
    for (int j = 0; j < 4; ++j) {
        float s = cs[j];
        s += __shfl_xor(s, 16, 64);
        s += __shfl_xor(s, 32, 64);
        if (lane < 16)
            atomicAdd(&sums[bz * ME + col0 + 16 * j + lane], s);
    }
}

// ---------------------------------------------------------------------------
// escale: eTs[b][d][m] = (bf16)(e[b][m][d] / colsum[b][m]).
// 64(m) x 32(d) tiles, LDS transpose. Grid (8, ME/64=16, D/32=32).
// Numerically identical rounding to the old gemm3 in-kernel B staging.
__global__ __launch_bounds__(256) void escale_kernel(
    const float* __restrict__ e, const float* __restrict__ sums,
    __bf16* __restrict__ eTs)
{
    const int D = 1024, ME = 1024;
    __shared__ float t[64][33];
    const int b = blockIdx.x, m0 = blockIdx.y * 64, d0 = blockIdx.z * 32;
    const int tid = threadIdx.x;
    const float* eb = e + (long long)b * ME * D;
    const int tx = tid & 31, ty = tid >> 5;   // 8 m-rows per pass
#pragma unroll
    for (int rr = ty; rr < 64; rr += 8)
        t[rr][tx] = eb[(long long)(m0 + rr) * D + d0 + tx];
    const int wx = tid & 63, wy = tid >> 6;   // 4 d-rows per pass
    const float rs = 1.0f / sums[b * ME + m0 + wx];
    __syncthreads();
    __bf16* ob = eTs + (long long)b * D * ME;
#pragma unroll
    for (int dd = wy; dd < 32; dd += 4)
        ob[(long long)(d0 + dd) * ME + m0 + wx] = (__bf16)(t[wx][dd] * rs);
}

// ---------------------------------------------------------------------------
// GEMM3: e_out = P @ eTs^T-ish (NT: A rows n, B rows d, K = m). Both operands
// bf16 via DMA staging -> pure MFMA loop, 32 KB LDS. A = P/s output handled by
// two extra grid z-slices (z=8,9; 64 rows each).
// Grid (8, 8, 10): z<8 GEMM (batch = x), z>=8 A-scale slices.
__global__ __launch_bounds__(256) void gemm3_kernel(
    const __bf16* __restrict__ P_bf, const __bf16* __restrict__ eTs,
    const float* __restrict__ sums,
    float* __restrict__ e_out, float* __restrict__ Aout)
{
    const int D = 1024, N = 1024, ME = 1024;
    const int tid = threadIdx.x;

    if (blockIdx.z >= 8) {   // A = P_bf / s  (64 rows per block)
        const int b = blockIdx.x, yb = blockIdx.y, half = blockIdx.z - 8;
        const long long base = ((long long)b * N + yb * 128 + half * 64) * ME;
        const float4 sv = *(const float4*)(sums + b * ME + tid * 4);
        const float4 rs = make_float4(1.f / sv.x, 1.f / sv.y, 1.f / sv.z, 1.f / sv.w);
        for (int it = 0; it < 64; ++it) {
            const long long o = base + (long long)it * ME + tid * 4;
            bf16_4 p = *(const bf16_4*)(P_bf + o);
            *(float4*)(Aout + o) =
                make_float4((float)p[0] * rs.x, (float)p[1] * rs.y,
                            (float)p[2] * rs.z, (float)p[3] * rs.w);
        }
        return;
    }

    __shared__ __bf16 sA[8192], sB[8192];
    const int lane = tid & 63, w = tid >> 6;
    const int fr = lane & 15, q = lane >> 4;
    const int wr = (w >> 1) * 64, wc = (w & 1) * 64;
    const int bz = blockIdx.x, rowb = blockIdx.y, colb = blockIdx.z;

    const __bf16* pA = P_bf + ((long long)bz * N + rowb * 128) * ME;
    const __bf16* pB = eTs  + ((long long)bz * D + colb * 128) * ME;

    f32_4 acc[4][4];
#pragma unroll
    for (int i = 0; i < 4; ++i)
#pragma unroll
        for (int j = 0; j < 4; ++j) acc[i][j] = (f32_4){0.f, 0.f, 0.f, 0.f};

    for (int k0 = 0; k0 < ME; k0 += 64) {
        stage_bf16(pA, ME, k0, sA, tid);
        stage_bf16(pB, ME, k0, sB, tid);
        __syncthreads();
#pragma unroll
        for (int ch = 0; ch < 2; ++ch) {
            bf16_8 ah[4], bh[4];
#pragma unroll
            for (int i = 0; i < 4; ++i) {
                ah[i] = *(const bf16_8*)(sA + frag_off(wr + 16 * i + fr, ch * 4 + q));
                bh[i] = *(const bf16_8*)(sB + frag_off(wc + 16 * i + fr, ch * 4 + q));
            }
#pragma unroll
            for (int i = 0; i < 4; ++i)
#pragma unroll
                for (int j = 0; j < 4; ++j)
                    acc[i][j] = __builtin_amdgcn_mfma_f32_16x16x32_bf16(ah[i], bh[j], acc[i][j], 0, 0, 0);
        }
        __syncthreads();
    }

    const int row0 = rowb * 128 + wr;
    const int col0 = colb * 128 + wc;
#pragma unroll
    for (int i = 0; i < 4; ++i)
#pragma unroll
        for (int j = 0; j < 4; ++j) {
            const int col = col0 + 16 * j + fr;
#pragma unroll
            for (int reg = 0; reg < 4; ++reg) {
                const int row = row0 + 16 * i + q * 4 + reg;
                e_out[(long long)bz * N * D + (long long)row * D + col] = acc[i][j][reg];
            }
        }
}

// ---------------------------------------------------------------------------
// prep: M transpose-split (1024 blocks) + zero sums (8 blocks).
__global__ __launch_bounds__(256) void prep_kernel(
    const float* __restrict__ M,
    __bf16* __restrict__ MT_hi, __bf16* __restrict__ MT_lo,
    float* __restrict__ sums, int D)
{
    __shared__ float t32[32][33];
    const int bid = blockIdx.x, tid = threadIdx.x;
    if (bid < 1024) {
        const int r0 = (bid >> 5) * 32, c0 = (bid & 31) * 32;
        const int tx = tid & 31, ty = tid >> 5;
#pragma unroll
        for (int rr = ty; rr < 32; rr += 8)
            t32[rr][tx] = M[(long long)(r0 + rr) * D + c0 + tx];
        __syncthreads();
#pragma unroll
        for (int cc = ty; cc < 32; cc += 8) {
            const float v = t32[tx][cc];
            const long long o = (long long)(c0 + cc) * D + r0 + tx;
            const __bf16 h = (__bf16)v;
            MT_hi[o] = h;
            MT_lo[o] = (__bf16)(v - (float)h);
        }
    } else {
        const int i = ((bid - 1024) * 256 + tid) * 4;
        *(float4*)(sums + i) = make_float4(0.f, 0.f, 0.f, 0.f);
    }
}

// ---------------------------------------------------------------------------
// Fallback fp32 path (round-1 kernels).
#define TILE 128
#define KT 8
template<bool BT, int EPI>
__global__ __launch_bounds__(256) void gemm_kernel(
    const float* __restrict__ A, const float* __restrict__ B, float* __restrict__ C,
    long long sA, long long sB, long long sC, int Mrows, int Ncols, int K)
{
    __shared__ float As[KT][TILE + 4];
    __shared__ float Bs[KT][TILE + 4];
    const int bz = blockIdx.z;
    A += (long long)bz * sA; B += (long long)bz * sB; C += (long long)bz * sC;
    const int tid = threadIdx.x;
    const int row0 = blockIdx.y * TILE, col0 = blockIdx.x * TILE;
    const int ld_r = tid >> 1, ld_k4 = (tid & 1) * 4;
    const int bn_k = tid >> 5, bn_c4 = (tid & 31) * 4;
    const int tx = tid & 15, ty = tid >> 4;
    const int c0 = tx * 4, c1 = c0 + 64, r0 = ty * 4, r1 = r0 + 64;
    float acc[8][8];
#pragma unroll
    for (int i = 0; i < 8; i++)
#pragma unroll
        for (int j = 0; j < 8; j++) acc[i][j] = 0.f;
    for (int k0 = 0; k0 < K; k0 += KT) {
        float4 av = *(const float4*)(A + (long long)(row0 + ld_r) * K + k0 + ld_k4);
        float4 bv;
        if (BT) bv = *(const float4*)(B + (long long)(col0 + ld_r) * K + k0 + ld_k4);
        else    bv = *(const float4*)(B + (long long)(k0 + bn_k) * Ncols + col0 + bn_c4);
        __syncthreads();
        As[ld_k4 + 0][ld_r] = av.x; As[ld_k4 + 1][ld_r] = av.y;
        As[ld_k4 + 2][ld_r] = av.z; As[ld_k4 + 3][ld_r] = av.w;
        if (BT) {
            Bs[ld_k4 + 0][ld_r] = bv.x; Bs[ld_k4 + 1][ld_r] = bv.y;
            Bs[ld_k4 + 2][ld_r] = bv.z; Bs[ld_k4 + 3][ld_r] = bv.w;
        } else {
            *(float4*)&Bs[bn_k][bn_c4] = bv;
        }
        __syncthreads();
#pragma unroll
        for (int kk = 0; kk < KT; kk++) {
            float4 a0 = *(const float4*)&As[kk][r0];
            float4 a1 = *(const float4*)&As[kk][r1];
            float4 b0 = *(const float4*)&Bs[kk][c0];
            float4 b1 = *(const float4*)&Bs[kk][c1];
            float ar[8] = {a0.x, a0.y, a0.z, a0.w, a1.x, a1.y, a1.z, a1.w};
            float br[8] = {b0.x, b0.y, b0.z, b0.w, b1.x, b1.y, b1.z, b1.w};
#pragma unroll
            for (int i = 0; i < 8; i++)
#pragma unroll
                for (int j = 0; j < 8; j++) acc[i][j] += ar[i] * br[j];
        }
    }
#pragma unroll
    for (int i = 0; i < 8; i++) {
        const int rr = (i < 4) ? (r0 + i) : (r1 + i - 4);
        float* crow = C + (long long)(row0 + rr) * Ncols + col0;
        float v[8];
#pragma unroll
        for (int j = 0; j < 8; j++) v[j] = acc[i][j];
        if (EPI == 1) {
#pragma unroll
            for (int j = 0; j < 8; j++) {
                float s = 1.0f / (1.0f + __expf(-v[j]));
                v[j] = __expf(s);
            }
        }
        *(float4*)(crow + c0) = make_float4(v[0], v[1], v[2], v[3]);
        *(float4*)(crow + c1) = make_float4(v[4], v[5], v[6], v[7]);
    }
}

__global__ __launch_bounds__(256) void colsum_kernel(
    const float* __restrict__ P, float* __restrict__ sums, int Nn, int Mm, int chunk)
{
    const int g = blockIdx.x * 256 + threadIdx.x;
    const int b = g >> 10;
    const int m = g & 1023;
    const int n0 = blockIdx.y * chunk;
    const float* p = P + (long long)b * Nn * Mm + (long long)n0 * Mm + m;
    float s0 = 0.f, s1 = 0.f, s2 = 0.f, s3 = 0.f;
    for (int n = 0; n < chunk; n += 4) {
        s0 += p[(long long)(n + 0) * Mm];
        s1 += p[(long long)(n + 1) * Mm];
        s2 += p[(long long)(n + 2) * Mm];
        s3 += p[(long long)(n + 3) * Mm];
    }
    atomicAdd(&sums[g], (s0 + s1) + (s2 + s3));
}

__global__ __launch_bounds__(256) void scale_kernel(
    float* __restrict__ P, const float* __restrict__ sums)
{
    const long long base = (blockIdx.x * 256LL + threadIdx.x) * 4;
    const int b = (int)(base >> 20);
    const int col = (int)(base & 1023);
    float4 v = *(float4*)(P + base);
    const float4 s = *(const float4*)(sums + (b << 10) + col);
    v.x /= s.x; v.y /= s.y; v.z /= s.z; v.w /= s.w;
    *(float4*)(P + base) = v;
}

// ---------------------------------------------------------------------------
extern "C" void kernel_launch(void* const* d_in, const int* in_sizes, int n_in,
                              void* d_out, int out_size, void* d_ws, size_t ws_size,
                              hipStream_t stream)
{
    const int B = 8, N = 1024, ME = 1024, D = 1024;
    const float* z = (const float*)d_in[0];   // [B,N,D]
    const float* e = (const float*)d_in[1];   // [B,ME,D]
    const float* M = (const float*)d_in[2];   // [D,D]
    float* out   = (float*)d_out;
    float* e_out = out;                         // [B,N,D]
    float* Aout  = out + (long long)B * N * D;  // [B,N,ME]

    const size_t MB = 1024 * 1024;
    const size_t NEEDED = 52 * MB + (size_t)B * ME * sizeof(float);

    if (ws_size >= NEEDED) {
        char* W = (char*)d_ws;
        __bf16* MT_hi = (__bf16*)(W);             // 2 MB
        __bf16* MT_lo = (__bf16*)(W + 2 * MB);    // 2 MB
        __bf16* zM_hi = (__bf16*)(W + 4 * MB);    // 16 MB (reused as eTs after gemm2)
        __bf16* zM_lo = (__bf16*)(W + 20 * MB);   // 16 MB
        __bf16* P_bf  = (__bf16*)(W + 36 * MB);   // 16 MB
        float*  sums  = (float*)(W + 52 * MB);    // 32 KB
        __bf16* eTs   = zM_hi;                    // alias: zM dead after gemm2

        // 1) prep: M^T hi/lo + zero sums.
        prep_kernel<<<dim3(1032), 256, 0, stream>>>(M, MT_hi, MT_lo, sums, D);

        // 2) GEMM1: zM = z @ M (z self-staged from fp32).
        gemm1_kernel<<<dim3(8, 64, 1), 256, 0, stream>>>(z, MT_hi, MT_lo, zM_hi, zM_lo);

        // 3) GEMM2: P = exp(sigmoid(zM @ e^T)) -> bf16 + colsum atomics.
        gemm2_kernel<<<dim3(8, 8, 8), 256, 0, stream>>>(zM_hi, zM_lo, e, P_bf, sums);

        // 4) escale: eTs = (e/colsum)^T in bf16 (into zM_hi's buffer).
        escale_kernel<<<dim3(8, 16, 32), 256, 0, stream>>>(e, sums, eTs);

        // 5) GEMM3: e_out = P @ eTs (pure bf16 DMA GEMM); A = P/s extra slices.
        gemm3_kernel<<<dim3(8, 8, 10), 256, 0, stream>>>(P_bf, eTs, sums, e_out, Aout);
    } else {
        // fp32 fallback (round-1 path), needs 32 MB + 32 KB.
        float* zM   = (float*)d_ws;
        float* sums = (float*)((char*)d_ws + (size_t)B * N * D * 4);
        gemm_kernel<false, 0><<<dim3(ME / TILE, (B * N) / TILE, 1), 256, 0, stream>>>(
            z, M, zM, 0, 0, 0, B * N, D, D);
        gemm_kernel<true, 1><<<dim3(ME / TILE, N / TILE, B), 256, 0, stream>>>(
            zM, e, Aout, (long long)N * D, (long long)ME * D, (long long)N * ME, N, ME, D);
        hipMemsetAsync(sums, 0, (size_t)B * ME * sizeof(float), stream);
        colsum_kernel<<<dim3((B * ME) / 256, 8), 256, 0, stream>>>(Aout, sums, N, ME, N / 8);
        scale_kernel<<<dim3((B * N * ME / 4) / 256), 256, 0, stream>>>(Aout, sums);
        gemm_kernel<false, 0><<<dim3(D / TILE, N / TILE, B), 256, 0, stream>>>(
            Aout, e, e_out, (long long)N * ME, (long long)ME * D, (long long)N * D, N, D, ME);
    }
}